// Round 13
// baseline (521.283 us; speedup 1.0000x reference)
//
#include <hip/hip_runtime.h>
#include <hip/hip_bf16.h>
#include <math.h>

#define N_NODES 8192
#define IN_F    512
#define OUT_F   128
#define LRELU_A 0.2f
#define EPS_BN  1e-5f
#define MSH     40.0f                // static softmax shift (upper bound on lrelu(max s1+max s2))
#define NSPLIT  16
#define JSPAN   (N_NODES / NSPLIT)   // 512
#define NGRP    (JSPAN / 256)        // 2 mask groups of 256 j
#define TILE_I  64                   // 4 waves x 16 rows
#define ISTR    520                  // k_h LDS input row stride in shorts (512 + 8 pad)

typedef unsigned short u16;
typedef unsigned int   u32;
typedef unsigned long long u64;
typedef __attribute__((ext_vector_type(8))) short  short8;
typedef __attribute__((ext_vector_type(4))) float  floatx4;

__device__ __forceinline__ u16 f2bf_rtn(float x) {
    u32 u = __float_as_uint(x);
    return (u16)((u + 0x7fffu + ((u >> 16) & 1u)) >> 16);
}

// ballot-pack one row's 16B adj slice into mask regs; lane rr keeps it.
#define BALLOT4(vv, rr, MM) do {                                   \
    u64 b0 = __ballot((int)(vv).x > 0);                            \
    u64 b1 = __ballot((int)(vv).y > 0);                            \
    u64 b2 = __ballot((int)(vv).z > 0);                            \
    u64 b3 = __ballot((int)(vv).w > 0);                            \
    if (n == (rr)) {                                               \
        MM[0] = (u32)b0; MM[1] = (u32)(b0 >> 32);                  \
        MM[2] = (u32)b1; MM[3] = (u32)(b1 >> 32);                  \
        MM[4] = (u32)b2; MM[5] = (u32)(b2 >> 32);                  \
        MM[6] = (u32)b3; MM[7] = (u32)(b3 >> 32);                  \
    }                                                              \
} while (0)

// ---------------- hamF bf16 in MFMA fragment order; zero s1/s2/cs/cq ----------------
// hamF[((kappa*4 + quad)*128 + c)*8 + e]  <=>  ham[c][k], k = kappa*32 + quad*8 + e.
__global__ __launch_bounds__(256) void k_hamT(const float* __restrict__ W, u16* __restrict__ hamF,
                                              float* __restrict__ s1, float* __restrict__ s2,
                                              float* __restrict__ cs, float* __restrict__ cq) {
    const int idx = blockIdx.x * 256 + threadIdx.x;   // 65536
    if (idx < N_NODES) { s1[idx] = 0.f; s2[idx] = 0.f; }
    if (idx < OUT_F)   { cs[idx] = 0.f; cq[idx] = 0.f; }
    const int c = idx >> 9, k = idx & 511;
    const int b = c >> 5, cc = c & 31, kp = k >> 7, kq = k & 127;
    const u32 NEGMASK = 0x284Eu;     // bit (b*4+kp) set => sign -1
    const float sg = ((NEGMASK >> (b * 4 + kp)) & 1u) ? -1.f : 1.f;
    const int kappa = k >> 5, q = (k >> 3) & 3, e = k & 7;
    hamF[((kappa * 4 + q) * 128 + c) * 8 + e] = f2bf_rtn(sg * W[kq * 128 + (b ^ kp) * 32 + cc]);
}

// ---------------- h = input @ ham via MFMA; LDS-staged bf16 A (once), fragment-ordered B ----------------
// grid 512 x 256 thr. Block: 16 i-rows x 128 c; wave w owns K-slice [w*128, w*128+128).
// Epilogue emits hTF in MFMA-fragment order: addr(i,c) = ((i>>5)*128 + c)*32 + (i&31).
__global__ __launch_bounds__(256) void k_h(const float* __restrict__ inp, const u16* __restrict__ hamF,
                                           const float* __restrict__ a,
                                           u16* __restrict__ hTF, float* __restrict__ s1, float* __restrict__ s2) {
    __shared__ u16 inA[16 * ISTR];         // 16640 B bf16 input tile
    __shared__ float red[4][128][20];      // 40960 B; [wave][c][i_local(16)+pad4]
    const int t = threadIdx.x;
    const int lane = t & 63, wid = t >> 6;
    const int quad = lane >> 4, n = lane & 15;
    const int i0 = blockIdx.x * 16;
    const int kb = wid * 128;

    // stage 16 rows x 512 f32 -> bf16 LDS, coalesced (4KB contiguous per pass)
#pragma unroll
    for (int u = 0; u < 8; ++u) {
        float4 v = *(const float4*)&inp[(size_t)i0 * IN_F + u * 1024 + t * 4];
        const int r = u * 2 + (t >> 7);
        const int col = (t & 127) * 4;
        u64 pk = (u64)f2bf_rtn(v.x) | ((u64)f2bf_rtn(v.y) << 16)
               | ((u64)f2bf_rtn(v.z) << 32) | ((u64)f2bf_rtn(v.w) << 48);
        *(u64*)&inA[r * ISTR + col] = pk;
    }
    __syncthreads();

    floatx4 acc[8];
#pragma unroll
    for (int ct = 0; ct < 8; ++ct) acc[ct] = (floatx4){0.f, 0.f, 0.f, 0.f};

#pragma unroll
    for (int ks = 0; ks < 4; ++ks) {
        short8 fa = *(const short8*)&inA[n * ISTR + kb + ks * 32 + quad * 8];
#pragma unroll
        for (int ct = 0; ct < 8; ++ct) {
            short8 fb = *(const short8*)&hamF[((wid * 4 + ks) * 4 + quad) * 1024 + (ct * 16 + n) * 8];
            acc[ct] = __builtin_amdgcn_mfma_f32_16x16x32_bf16(fa, fb, acc[ct], 0, 0, 0);
        }
    }

    // s1/s2 partials (this wave's K-slice; full c) -> global atomics
    {
        float p1[4] = {0.f, 0.f, 0.f, 0.f}, p2[4] = {0.f, 0.f, 0.f, 0.f};
#pragma unroll
        for (int ct = 0; ct < 8; ++ct) {
            const int c = ct * 16 + n;
            const float a1v = a[c], a2v = a[OUT_F + c];
#pragma unroll
            for (int r = 0; r < 4; ++r) { p1[r] += acc[ct][r] * a1v; p2[r] += acc[ct][r] * a2v; }
        }
#pragma unroll
        for (int m = 1; m < 16; m <<= 1) {
#pragma unroll
            for (int r = 0; r < 4; ++r) {
                p1[r] += __shfl_xor(p1[r], m, 64);
                p2[r] += __shfl_xor(p2[r], m, 64);
            }
        }
        if (n == 0) {
#pragma unroll
            for (int r = 0; r < 4; ++r) {
                atomicAdd(&s1[i0 + quad * 4 + r], p1[r]);
                atomicAdd(&s2[i0 + quad * 4 + r], p2[r]);
            }
        }
    }

    // cross-wave reduce -> hTF (bf16, MFMA-fragment order)
#pragma unroll
    for (int ct = 0; ct < 8; ++ct)
        *(float4*)&red[wid][ct * 16 + n][quad * 4] = *(float4*)&acc[ct];
    __syncthreads();

    {
        const int c = t >> 1, ih = (t & 1) * 8;
        float v[8];
#pragma unroll
        for (int e = 0; e < 8; ++e)
            v[e] = red[0][c][ih + e] + red[1][c][ih + e] + red[2][c][ih + e] + red[3][c][ih + e];
        uint4 pk;
        pk.x = (u32)f2bf_rtn(v[0]) | ((u32)f2bf_rtn(v[1]) << 16);
        pk.y = (u32)f2bf_rtn(v[2]) | ((u32)f2bf_rtn(v[3]) << 16);
        pk.z = (u32)f2bf_rtn(v[4]) | ((u32)f2bf_rtn(v[5]) << 16);
        pk.w = (u32)f2bf_rtn(v[6]) | ((u32)f2bf_rtn(v[7]) << 16);
        const int i = i0 + ih;     // 8 consecutive i within one 32-block (16B-aligned)
        *(uint4*)&hTF[((size_t)(i >> 5) * 128 + c) * 32 + (i & 31)] = pk;
    }
}

// ---------------- fused MFMA attention: barrier-free j-loop, fb loads issued BEFORE softmax VALU ----------------
// grid (128, NSPLIT=16) x 256 thr. Block: 64 i x 128 c over JSPAN=512 j; 2 groups x 4 chunks of 64 j.
// R12 post-mortem: direct-L2 fb was right (L1 serves the 4-wave redundancy: all waves read identical
// fragment data), but loads were issued AFTER the fa-build -> ~500cyc exposed L2 latency per chunk.
// Fix: per ks-group, issue the 8 fb loads FIRST, then build fa (~160 VALU instr covers ~250cyc L2
// hit), then MFMA. Only one ks-group (32 VGPR) in flight -> peak ~115 VGPR, inside the 128-reg tier
// (R9/R10 spill-flip lesson). No hs LDS, no per-chunk barriers (one barrier total, for s2s).
__global__ __launch_bounds__(256, 4) void k_att(const int* __restrict__ adj, const u16* __restrict__ hTF,
                                                const float* __restrict__ s1, const float* __restrict__ s2,
                                                float* __restrict__ Opart, float* __restrict__ Lpart) {
    __shared__ float s2s[JSPAN];           // 2 KB (the only LDS)
    const int t = threadIdx.x;
    const int lane = t & 63, wid = t >> 6;
    const int quad = lane >> 4, n = lane & 15;
    const int i0 = blockIdx.x * TILE_I;
    const int jbase = blockIdx.y * JSPAN;
    const int jb32 = blockIdx.y * (JSPAN / 32);     // jbase in 32-j blocks
    const int i_lane = i0 + wid * 16 + n;
    const float s1v = s1[i_lane];

    if (t < JSPAN / 4)
        *(float4*)&s2s[t * 4] = *(const float4*)&s2[jbase + t * 4];

    // ---- Phase A: ballot-pack adj rows; lane n keeps row (wid*16+n)'s masks in regs ----
    u32 M[NGRP][8];
#pragma unroll
    for (int g = 0; g < NGRP; ++g)
#pragma unroll
        for (int w = 0; w < 8; ++w) M[g][w] = 0u;
    {
        const size_t rowbase = (size_t)(i0 + wid * 16);
        const int* aj = adj + jbase + lane * 4;
#pragma unroll 4
        for (int rr = 0; rr < 16; ++rr) {
            const int* ap = aj + (rowbase + rr) * N_NODES;
            uint4 v[NGRP];
#pragma unroll
            for (int g = 0; g < NGRP; ++g) v[g] = *(const uint4*)(ap + g * 256);
#pragma unroll
            for (int g = 0; g < NGRP; ++g) BALLOT4(v[g], rr, M[g]);
        }
    }
    __syncthreads();   // s2s visible; the ONLY barrier in this kernel

    floatx4 acc[8];
#pragma unroll
    for (int ct = 0; ct < 8; ct++) acc[ct] = (floatx4){0.f, 0.f, 0.f, 0.f};
    float Lacc = 0.f;

    const u16* hfl = hTF + (size_t)n * 32 + quad * 8;   // lane-fixed fragment offset

#pragma unroll
    for (int g = 0; g < NGRP; ++g) {
#pragma unroll
        for (int chi = 0; chi < 4; ++chi) {
            const int ch = g * 4 + chi;
#pragma unroll
            for (int ks = 0; ks < 2; ++ks) {
                // 1) issue the 8 fb loads FIRST (1KB/wave coalesced; L2/L1-resident hTF)
                const u16* hb = hfl + (size_t)(jb32 + ch * 2 + ks) * 4096;
                short8 fbv[8];
#pragma unroll
                for (int ct = 0; ct < 8; ++ct) fbv[ct] = *(const short8*)(hb + ct * 512);
                // 2) build fa for this ks (~160 VALU instr — covers the fb load latency)
                const int jl = ch * 64 + ks * 32 + quad * 8;
                float4 sa = *(const float4*)&s2s[jl];
                float4 sb = *(const float4*)&s2s[jl + 4];
                const float sv[8] = {sa.x, sa.y, sa.z, sa.w, sb.x, sb.y, sb.z, sb.w};
                union { u32 u[4]; short8 s; } cv;
#pragma unroll
                for (int jh = 0; jh < 4; ++jh) {
                    float w2[2];
#pragma unroll
                    for (int e = 0; e < 2; ++e) {
                        const int jj = jh * 2 + e;
                        const u32 word = M[g][(jj & 3) * 2 + (chi >> 1)];   // all-static reg index
                        const int sh = (chi & 1) * 16 + ks * 8 + quad * 2 + (jj >> 2);
                        const u32 mbit = (word >> sh) & 1u;
                        float sc = s1v + sv[jj];
                        sc = fmaxf(sc, LRELU_A * sc);
                        float w = mbit ? __expf(sc - MSH) : 0.f;
                        Lacc += w;
                        w2[e] = w;
                    }
                    cv.u[jh] = (u32)f2bf_rtn(w2[0]) | ((u32)f2bf_rtn(w2[1]) << 16);
                }
                // 3) 8 MFMAs consume the landed fb data
#pragma unroll
                for (int ct = 0; ct < 8; ++ct)
                    acc[ct] = __builtin_amdgcn_mfma_f32_16x16x32_bf16(cv.s, fbv[ct], acc[ct], 0, 0, 0);
            }
        }
    }

    // L row-sum across quads
    Lacc += __shfl_xor(Lacc, 16, 64);
    Lacc += __shfl_xor(Lacc, 32, 64);
    if (lane < 16)
        Lpart[(size_t)blockIdx.y * N_NODES + i_lane] = Lacc;

    // O partials (C layout: row = quad*4+reg, col = ct*16+n)
    const size_t obase = (size_t)blockIdx.y * N_NODES * OUT_F;
#pragma unroll
    for (int ct = 0; ct < 8; ++ct) {
#pragma unroll
        for (int r = 0; r < 4; ++r) {
            const int i = i0 + wid * 16 + quad * 4 + r;
            Opart[obase + (size_t)i * OUT_F + ct * 16 + n] = acc[ct][r];
        }
    }
}

// ---------------- combine partials, normalize, column stats via atomics ----------------
// grid 512 x 256 thr; block = 16 i-rows
__global__ __launch_bounds__(256) void k_comb(const float* __restrict__ Opart, const float* __restrict__ Lpart,
                                              float* __restrict__ hp, float* __restrict__ cs, float* __restrict__ cq) {
    const int t = threadIdx.x;
    const int c = t & 127, half = t >> 7;
    const int ibase = blockIdx.x * 16;
    float sv = 0.f, sq = 0.f;
    for (int k = 0; k < 8; k++) {
        const int i = ibase + half + (k << 1);
        float o = 0.f, L = 0.f;
#pragma unroll
        for (int s = 0; s < NSPLIT; s++) {
            o += Opart[((size_t)s * N_NODES + i) * OUT_F + c];
            L += Lpart[(size_t)s * N_NODES + i];
        }
        float v = L > 0.f ? o / L : 0.f;
        hp[(size_t)i * OUT_F + c] = v;
        sv += v; sq += v * v;
    }
    __shared__ float red[256];
    red[t] = sv; __syncthreads();
    if (half == 0) atomicAdd(&cs[c], sv + red[t + 128]);
    __syncthreads(); red[t] = sq; __syncthreads();
    if (half == 0) atomicAdd(&cq[c], sq + red[t + 128]);
}

// ---------------- batchnorm + elu + f32 out ----------------
__global__ __launch_bounds__(256) void k_bn(const float* __restrict__ hp, const float* __restrict__ cs,
                                            const float* __restrict__ cq, const float* __restrict__ gamma,
                                            const float* __restrict__ beta, float* __restrict__ out) {
    const int idx = blockIdx.x * 256 + threadIdx.x;   // 1M
    const int c = idx & 127;
    const float mean = cs[c] * (1.f / N_NODES);
    const float var  = cq[c] * (1.f / N_NODES) - mean * mean;
    float x = (hp[idx] - mean) * rsqrtf(var + EPS_BN) * gamma[c] + beta[c];
    x = x > 0.f ? x : expm1f(x);
    out[idx] = x;
}

extern "C" void kernel_launch(void* const* d_in, const int* in_sizes, int n_in,
                              void* d_out, int out_size, void* d_ws, size_t ws_size,
                              hipStream_t stream) {
    (void)in_sizes; (void)n_in; (void)out_size; (void)ws_size;
    const float* inp   = (const float*)d_in[0];
    const int*   adj   = (const int*)d_in[1];
    const float* W     = (const float*)d_in[2];
    const float* a     = (const float*)d_in[3];
    const float* gamma = (const float*)d_in[4];
    const float* beta  = (const float*)d_in[5];
    float* out = (float*)d_out;

    char* wsb = (char*)d_ws;
    u16*   hamF = (u16*)wsb;   wsb += (size_t)OUT_F * IN_F * 2;               // 128 KB
    u16*   hTF  = (u16*)wsb;   wsb += (size_t)OUT_F * N_NODES * 2;            // 2 MB (fragment order)
    float* s1   = (float*)wsb; wsb += N_NODES * 4;
    float* s2   = (float*)wsb; wsb += N_NODES * 4;
    float* Op   = (float*)wsb; wsb += (size_t)NSPLIT * N_NODES * OUT_F * 4;   // 64 MB
    float* Lp   = (float*)wsb; wsb += (size_t)NSPLIT * N_NODES * 4;
    float* hp   = (float*)wsb; wsb += (size_t)N_NODES * OUT_F * 4;            // 4 MB
    float* cs   = (float*)wsb; wsb += OUT_F * 4;
    float* cq   = (float*)wsb; wsb += OUT_F * 4;

    hipLaunchKernelGGL(k_hamT, dim3(256), dim3(256), 0, stream, W, hamF, s1, s2, cs, cq);
    hipLaunchKernelGGL(k_h,    dim3(512), dim3(256), 0, stream, inp, hamF, a, hTF, s1, s2);
    hipLaunchKernelGGL(k_att,  dim3(128, NSPLIT), dim3(256), 0, stream, adj, hTF, s1, s2, Op, Lp);
    hipLaunchKernelGGL(k_comb, dim3(512), dim3(256), 0, stream, Op, Lp, hp, cs, cq);
    hipLaunchKernelGGL(k_bn,   dim3(4096), dim3(256), 0, stream, hp, cs, cq, gamma, beta, out);
}

// Round 14
// 442.490 us; speedup vs baseline: 1.1781x; 1.1781x over previous
//
#include <hip/hip_runtime.h>
#include <hip/hip_bf16.h>
#include <math.h>

#define N_NODES 8192
#define IN_F    512
#define OUT_F   128
#define LRELU_A 0.2f
#define EPS_BN  1e-5f
#define MSH     40.0f                // static softmax shift (upper bound on lrelu(max s1+max s2))
#define NSPLIT  16
#define JSPAN   (N_NODES / NSPLIT)   // 512
#define NGRP    (JSPAN / 256)        // 2 mask groups of 256 j
#define TILE_I  64                   // 4 waves x 16 rows
#define ISTR    520                  // k_h LDS input row stride in shorts (512 + 8 pad)

typedef unsigned short u16;
typedef unsigned int   u32;
typedef unsigned long long u64;
typedef __attribute__((ext_vector_type(8))) short  short8;
typedef __attribute__((ext_vector_type(4))) float  floatx4;

__device__ __forceinline__ u16 f2bf_rtn(float x) {
    u32 u = __float_as_uint(x);
    return (u16)((u + 0x7fffu + ((u >> 16) & 1u)) >> 16);
}

// ballot-pack one row's 16B adj slice into mask regs; lane rr keeps it.
#define BALLOT4(vv, rr, MM) do {                                   \
    u64 b0 = __ballot((int)(vv).x > 0);                            \
    u64 b1 = __ballot((int)(vv).y > 0);                            \
    u64 b2 = __ballot((int)(vv).z > 0);                            \
    u64 b3 = __ballot((int)(vv).w > 0);                            \
    if (n == (rr)) {                                               \
        MM[0] = (u32)b0; MM[1] = (u32)(b0 >> 32);                  \
        MM[2] = (u32)b1; MM[3] = (u32)(b1 >> 32);                  \
        MM[4] = (u32)b2; MM[5] = (u32)(b2 >> 32);                  \
        MM[6] = (u32)b3; MM[7] = (u32)(b3 >> 32);                  \
    }                                                              \
} while (0)

// ---------------- hamF bf16 in MFMA fragment order; zero s1/s2/cs/cq ----------------
// hamF[((kappa*4 + quad)*128 + c)*8 + e]  <=>  ham[c][k], k = kappa*32 + quad*8 + e.
__global__ __launch_bounds__(256) void k_hamT(const float* __restrict__ W, u16* __restrict__ hamF,
                                              float* __restrict__ s1, float* __restrict__ s2,
                                              float* __restrict__ cs, float* __restrict__ cq) {
    const int idx = blockIdx.x * 256 + threadIdx.x;   // 65536
    if (idx < N_NODES) { s1[idx] = 0.f; s2[idx] = 0.f; }
    if (idx < OUT_F)   { cs[idx] = 0.f; cq[idx] = 0.f; }
    const int c = idx >> 9, k = idx & 511;
    const int b = c >> 5, cc = c & 31, kp = k >> 7, kq = k & 127;
    const u32 NEGMASK = 0x284Eu;     // bit (b*4+kp) set => sign -1
    const float sg = ((NEGMASK >> (b * 4 + kp)) & 1u) ? -1.f : 1.f;
    const int kappa = k >> 5, q = (k >> 3) & 3, e = k & 7;
    hamF[((kappa * 4 + q) * 128 + c) * 8 + e] = f2bf_rtn(sg * W[kq * 128 + (b ^ kp) * 32 + cc]);
}

// ---------------- h = input @ ham via MFMA; LDS-staged bf16 A (once), fragment-ordered B ----------------
// grid 512 x 256 thr. Block: 16 i-rows x 128 c; wave w owns K-slice [w*128, w*128+128).
__global__ __launch_bounds__(256) void k_h(const float* __restrict__ inp, const u16* __restrict__ hamF,
                                           const float* __restrict__ a,
                                           u16* __restrict__ hT, float* __restrict__ s1, float* __restrict__ s2) {
    __shared__ u16 inA[16 * ISTR];         // 16640 B bf16 input tile
    __shared__ float red[4][128][20];      // 40960 B; [wave][c][i_local(16)+pad4]
    const int t = threadIdx.x;
    const int lane = t & 63, wid = t >> 6;
    const int quad = lane >> 4, n = lane & 15;
    const int i0 = blockIdx.x * 16;
    const int kb = wid * 128;

    // stage 16 rows x 512 f32 -> bf16 LDS, coalesced (4KB contiguous per pass)
#pragma unroll
    for (int u = 0; u < 8; ++u) {
        float4 v = *(const float4*)&inp[(size_t)i0 * IN_F + u * 1024 + t * 4];
        const int r = u * 2 + (t >> 7);
        const int col = (t & 127) * 4;
        u64 pk = (u64)f2bf_rtn(v.x) | ((u64)f2bf_rtn(v.y) << 16)
               | ((u64)f2bf_rtn(v.z) << 32) | ((u64)f2bf_rtn(v.w) << 48);
        *(u64*)&inA[r * ISTR + col] = pk;
    }
    __syncthreads();

    floatx4 acc[8];
#pragma unroll
    for (int ct = 0; ct < 8; ++ct) acc[ct] = (floatx4){0.f, 0.f, 0.f, 0.f};

#pragma unroll
    for (int ks = 0; ks < 4; ++ks) {
        short8 fa = *(const short8*)&inA[n * ISTR + kb + ks * 32 + quad * 8];
#pragma unroll
        for (int ct = 0; ct < 8; ++ct) {
            short8 fb = *(const short8*)&hamF[((wid * 4 + ks) * 4 + quad) * 1024 + (ct * 16 + n) * 8];
            acc[ct] = __builtin_amdgcn_mfma_f32_16x16x32_bf16(fa, fb, acc[ct], 0, 0, 0);
        }
    }

    // s1/s2 partials (this wave's K-slice; full c) -> global atomics
    {
        float p1[4] = {0.f, 0.f, 0.f, 0.f}, p2[4] = {0.f, 0.f, 0.f, 0.f};
#pragma unroll
        for (int ct = 0; ct < 8; ++ct) {
            const int c = ct * 16 + n;
            const float a1v = a[c], a2v = a[OUT_F + c];
#pragma unroll
            for (int r = 0; r < 4; ++r) { p1[r] += acc[ct][r] * a1v; p2[r] += acc[ct][r] * a2v; }
        }
#pragma unroll
        for (int m = 1; m < 16; m <<= 1) {
#pragma unroll
            for (int r = 0; r < 4; ++r) {
                p1[r] += __shfl_xor(p1[r], m, 64);
                p2[r] += __shfl_xor(p2[r], m, 64);
            }
        }
        if (n == 0) {
#pragma unroll
            for (int r = 0; r < 4; ++r) {
                atomicAdd(&s1[i0 + quad * 4 + r], p1[r]);
                atomicAdd(&s2[i0 + quad * 4 + r], p2[r]);
            }
        }
    }

    // cross-wave reduce -> hT (bf16, [c][i] layout)
#pragma unroll
    for (int ct = 0; ct < 8; ++ct)
        *(float4*)&red[wid][ct * 16 + n][quad * 4] = *(float4*)&acc[ct];
    __syncthreads();

    {
        const int c = t >> 1, ih = (t & 1) * 8;
        float v[8];
#pragma unroll
        for (int e = 0; e < 8; ++e)
            v[e] = red[0][c][ih + e] + red[1][c][ih + e] + red[2][c][ih + e] + red[3][c][ih + e];
        uint4 pk;
        pk.x = (u32)f2bf_rtn(v[0]) | ((u32)f2bf_rtn(v[1]) << 16);
        pk.y = (u32)f2bf_rtn(v[2]) | ((u32)f2bf_rtn(v[3]) << 16);
        pk.z = (u32)f2bf_rtn(v[4]) | ((u32)f2bf_rtn(v[5]) << 16);
        pk.w = (u32)f2bf_rtn(v[6]) | ((u32)f2bf_rtn(v[7]) << 16);
        *(uint4*)&hT[(size_t)c * N_NODES + i0 + ih] = pk;
    }
}

// ---------------- fused MFMA attention (R6-validated body) at NSPLIT=16 ----------------
// grid (128, NSPLIT=16) x 256 thr. Block: 64 i x 128 c over JSPAN=512 j; 2 groups x 4 chunks of 64 j.
// 2048 blocks / (4 blocks/CU x 256 CU) = 2 residency GENERATIONS: gen-2's adj phase A overlaps
// gen-1's j-loop (cross-generation TLP hides the compulsory 256 MB adj stream that R5/R7 proved
// cannot be hidden intra-block). Masks M[2][8] = 16 regs (was 32): lower pressure, safer vs the
// R9/R10 spill-tier flip (keep __expf+MSH exactly — the exp2 rewrite is what flipped the allocator).
__global__ __launch_bounds__(256, 4) void k_att(const int* __restrict__ adj, const u16* __restrict__ hT,
                                                const float* __restrict__ s1, const float* __restrict__ s2,
                                                float* __restrict__ Opart, float* __restrict__ Lpart) {
    __shared__ u16 hs[2][128 * 64];        // 2 x 16384 B, XOR-swizzled rows
    __shared__ float s2s[JSPAN];           // 2 KB
    const int t = threadIdx.x;
    const int lane = t & 63, wid = t >> 6;
    const int quad = lane >> 4, n = lane & 15;
    const int i0 = blockIdx.x * TILE_I;
    const int jbase = blockIdx.y * JSPAN;
    const int i_lane = i0 + wid * 16 + n;
    const float s1v = s1[i_lane];
    const int scr = t >> 3, scj = (t & 7) * 8;      // hT staging: 32 c-rows/pass, 16 B/thread

    if (t < JSPAN / 4)
        *(float4*)&s2s[t * 4] = *(const float4*)&s2[jbase + t * 4];

    // ---- Phase A: ballot-pack adj rows; lane n keeps row (wid*16+n)'s masks in regs ----
    u32 M[NGRP][8];
#pragma unroll
    for (int g = 0; g < NGRP; ++g)
#pragma unroll
        for (int w = 0; w < 8; ++w) M[g][w] = 0u;
    {
        const size_t rowbase = (size_t)(i0 + wid * 16);
        const int* aj = adj + jbase + lane * 4;
#pragma unroll 4
        for (int rr = 0; rr < 16; ++rr) {
            const int* ap = aj + (rowbase + rr) * N_NODES;
            uint4 v[NGRP];
#pragma unroll
            for (int g = 0; g < NGRP; ++g) v[g] = *(const uint4*)(ap + g * 256);
#pragma unroll
            for (int g = 0; g < NGRP; ++g) BALLOT4(v[g], rr, M[g]);
        }
    }

    // ---- stage hT chunk 0 (swizzled write) ----
#pragma unroll
    for (int ps = 0; ps < 4; ++ps) {
        const int cr = ps * 32 + scr;
        uint4 v = *(const uint4*)&hT[(size_t)cr * N_NODES + jbase + scj];
        *(uint4*)&hs[0][cr * 64 + (scj ^ ((cr & 7) * 8))] = v;
    }
    __syncthreads();

    floatx4 acc[8];
#pragma unroll
    for (int ct = 0; ct < 8; ct++) acc[ct] = (floatx4){0.f, 0.f, 0.f, 0.f};
    float Lacc = 0.f;

#pragma unroll
    for (int g = 0; g < NGRP; ++g) {
#pragma unroll
        for (int chi = 0; chi < 4; ++chi) {
            const int ch = g * 4 + chi;
            const int cur = ch & 1;
            const bool more = (ch + 1 < NGRP * 4);
            // prefetch next chunk's hT (regs; LDS write after compute)
            uint4 H[4];
            if (more) {
#pragma unroll
                for (int ps = 0; ps < 4; ++ps) {
                    const int cr = ps * 32 + scr;
                    H[ps] = *(const uint4*)&hT[(size_t)cr * N_NODES + jbase + (ch + 1) * 64 + scj];
                }
            }
            // build A-frags (attention weights) for this chunk's 64 j; s2 from LDS (lgkmcnt)
            short8 fa[2];
#pragma unroll
            for (int ks = 0; ks < 2; ++ks) {
                const int jl = ch * 64 + ks * 32 + quad * 8;
                float4 sa = *(const float4*)&s2s[jl];
                float4 sb = *(const float4*)&s2s[jl + 4];
                const float sv[8] = {sa.x, sa.y, sa.z, sa.w, sb.x, sb.y, sb.z, sb.w};
                union { u32 u[4]; short8 s; } cv;
#pragma unroll
                for (int jh = 0; jh < 4; ++jh) {
                    float w2[2];
#pragma unroll
                    for (int e = 0; e < 2; ++e) {
                        const int jj = jh * 2 + e;
                        const u32 word = M[g][(jj & 3) * 2 + (chi >> 1)];   // all-static reg index
                        const int sh = (chi & 1) * 16 + ks * 8 + quad * 2 + (jj >> 2);
                        const u32 mbit = (word >> sh) & 1u;
                        float sc = s1v + sv[jj];
                        sc = fmaxf(sc, LRELU_A * sc);
                        float w = mbit ? __expf(sc - MSH) : 0.f;
                        Lacc += w;
                        w2[e] = w;
                    }
                    cv.u[jh] = (u32)f2bf_rtn(w2[0]) | ((u32)f2bf_rtn(w2[1]) << 16);
                }
                fa[ks] = cv.s;
            }
            // 16 MFMAs from LDS (swizzled reads: conflict-free)
#pragma unroll
            for (int ct = 0; ct < 8; ++ct) {
                const int rb = ct * 16 + n;
                const int sw = (rb & 7) * 8;
                short8 fb0 = *(const short8*)&hs[cur][rb * 64 + ((quad * 8) ^ sw)];
                short8 fb1 = *(const short8*)&hs[cur][rb * 64 + ((32 + quad * 8) ^ sw)];
                acc[ct] = __builtin_amdgcn_mfma_f32_16x16x32_bf16(fa[0], fb0, acc[ct], 0, 0, 0);
                acc[ct] = __builtin_amdgcn_mfma_f32_16x16x32_bf16(fa[1], fb1, acc[ct], 0, 0, 0);
            }
            // write prefetched chunk to alternate buffer (swizzled)
            if (more) {
#pragma unroll
                for (int ps = 0; ps < 4; ++ps) {
                    const int cr = ps * 32 + scr;
                    *(uint4*)&hs[cur ^ 1][cr * 64 + (scj ^ ((cr & 7) * 8))] = H[ps];
                }
            }
            __syncthreads();
        }
    }

    // L row-sum across quads
    Lacc += __shfl_xor(Lacc, 16, 64);
    Lacc += __shfl_xor(Lacc, 32, 64);
    if (lane < 16)
        Lpart[(size_t)blockIdx.y * N_NODES + i_lane] = Lacc;

    // O partials (C layout: row = quad*4+reg, col = ct*16+n)
    const size_t obase = (size_t)blockIdx.y * N_NODES * OUT_F;
#pragma unroll
    for (int ct = 0; ct < 8; ++ct) {
#pragma unroll
        for (int r = 0; r < 4; ++r) {
            const int i = i0 + wid * 16 + quad * 4 + r;
            Opart[obase + (size_t)i * OUT_F + ct * 16 + n] = acc[ct][r];
        }
    }
}

// ---------------- combine partials, normalize, column stats via atomics ----------------
// grid 512 x 256 thr; block = 16 i-rows
__global__ __launch_bounds__(256) void k_comb(const float* __restrict__ Opart, const float* __restrict__ Lpart,
                                              float* __restrict__ hp, float* __restrict__ cs, float* __restrict__ cq) {
    const int t = threadIdx.x;
    const int c = t & 127, half = t >> 7;
    const int ibase = blockIdx.x * 16;
    float sv = 0.f, sq = 0.f;
    for (int k = 0; k < 8; k++) {
        const int i = ibase + half + (k << 1);
        float o = 0.f, L = 0.f;
#pragma unroll
        for (int s = 0; s < NSPLIT; s++) {
            o += Opart[((size_t)s * N_NODES + i) * OUT_F + c];
            L += Lpart[(size_t)s * N_NODES + i];
        }
        float v = L > 0.f ? o / L : 0.f;
        hp[(size_t)i * OUT_F + c] = v;
        sv += v; sq += v * v;
    }
    __shared__ float red[256];
    red[t] = sv; __syncthreads();
    if (half == 0) atomicAdd(&cs[c], sv + red[t + 128]);
    __syncthreads(); red[t] = sq; __syncthreads();
    if (half == 0) atomicAdd(&cq[c], sq + red[t + 128]);
}

// ---------------- batchnorm + elu + f32 out ----------------
__global__ __launch_bounds__(256) void k_bn(const float* __restrict__ hp, const float* __restrict__ cs,
                                            const float* __restrict__ cq, const float* __restrict__ gamma,
                                            const float* __restrict__ beta, float* __restrict__ out) {
    const int idx = blockIdx.x * 256 + threadIdx.x;   // 1M
    const int c = idx & 127;
    const float mean = cs[c] * (1.f / N_NODES);
    const float var  = cq[c] * (1.f / N_NODES) - mean * mean;
    float x = (hp[idx] - mean) * rsqrtf(var + EPS_BN) * gamma[c] + beta[c];
    x = x > 0.f ? x : expm1f(x);
    out[idx] = x;
}

extern "C" void kernel_launch(void* const* d_in, const int* in_sizes, int n_in,
                              void* d_out, int out_size, void* d_ws, size_t ws_size,
                              hipStream_t stream) {
    (void)in_sizes; (void)n_in; (void)out_size; (void)ws_size;
    const float* inp   = (const float*)d_in[0];
    const int*   adj   = (const int*)d_in[1];
    const float* W     = (const float*)d_in[2];
    const float* a     = (const float*)d_in[3];
    const float* gamma = (const float*)d_in[4];
    const float* beta  = (const float*)d_in[5];
    float* out = (float*)d_out;

    char* wsb = (char*)d_ws;
    u16*   hamF = (u16*)wsb;   wsb += (size_t)OUT_F * IN_F * 2;               // 128 KB
    u16*   hT   = (u16*)wsb;   wsb += (size_t)OUT_F * N_NODES * 2;            // 2 MB
    float* s1   = (float*)wsb; wsb += N_NODES * 4;
    float* s2   = (float*)wsb; wsb += N_NODES * 4;
    float* Op   = (float*)wsb; wsb += (size_t)NSPLIT * N_NODES * OUT_F * 4;   // 64 MB
    float* Lp   = (float*)wsb; wsb += (size_t)NSPLIT * N_NODES * 4;
    float* hp   = (float*)wsb; wsb += (size_t)N_NODES * OUT_F * 4;            // 4 MB
    float* cs   = (float*)wsb; wsb += OUT_F * 4;
    float* cq   = (float*)wsb; wsb += OUT_F * 4;

    hipLaunchKernelGGL(k_hamT, dim3(256), dim3(256), 0, stream, W, hamF, s1, s2, cs, cq);
    hipLaunchKernelGGL(k_h,    dim3(512), dim3(256), 0, stream, inp, hamF, a, hT, s1, s2);
    hipLaunchKernelGGL(k_att,  dim3(128, NSPLIT), dim3(256), 0, stream, adj, hT, s1, s2, Op, Lp);
    hipLaunchKernelGGL(k_comb, dim3(512), dim3(256), 0, stream, Op, Lp, hp, cs, cq);
    hipLaunchKernelGGL(k_bn,   dim3(4096), dim3(256), 0, stream, hp, cs, cq, gamma, beta, out);
}

// Round 15
// 425.814 us; speedup vs baseline: 1.2242x; 1.0392x over previous
//
#include <hip/hip_runtime.h>
#include <hip/hip_bf16.h>
#include <math.h>

#define N_NODES 8192
#define IN_F    512
#define OUT_F   128
#define LRELU_A 0.2f
#define EPS_BN  1e-5f
#define MSH     40.0f                // static softmax shift (upper bound on lrelu(max s1+max s2))
#define NSPLIT  16
#define JSPAN   (N_NODES / NSPLIT)   // 512
#define NGRP    (JSPAN / 256)        // 2 mask groups of 256 j
#define TILE_I  64                   // 4 waves x 16 rows
#define ISTR    520                  // k_h LDS input row stride in shorts (512 + 8 pad)

typedef unsigned short u16;
typedef unsigned int   u32;
typedef unsigned long long u64;
typedef __attribute__((ext_vector_type(8))) short  short8;
typedef __attribute__((ext_vector_type(4))) float  floatx4;

__device__ __forceinline__ u16 f2bf_rtn(float x) {
    u32 u = __float_as_uint(x);
    return (u16)((u + 0x7fffu + ((u >> 16) & 1u)) >> 16);
}

// ballot-pack one row's 16B adj slice into mask regs; lane rr keeps it.
#define BALLOT4(vv, rr, MM) do {                                   \
    u64 b0 = __ballot((int)(vv).x > 0);                            \
    u64 b1 = __ballot((int)(vv).y > 0);                            \
    u64 b2 = __ballot((int)(vv).z > 0);                            \
    u64 b3 = __ballot((int)(vv).w > 0);                            \
    if (n == (rr)) {                                               \
        MM[0] = (u32)b0; MM[1] = (u32)(b0 >> 32);                  \
        MM[2] = (u32)b1; MM[3] = (u32)(b1 >> 32);                  \
        MM[4] = (u32)b2; MM[5] = (u32)(b2 >> 32);                  \
        MM[6] = (u32)b3; MM[7] = (u32)(b3 >> 32);                  \
    }                                                              \
} while (0)

// ---------------- hamF bf16 in MFMA fragment order; zero s1/s2/cs/cq ----------------
// hamF[((kappa*4 + quad)*128 + c)*8 + e]  <=>  ham[c][k], k = kappa*32 + quad*8 + e.
__global__ __launch_bounds__(256) void k_hamT(const float* __restrict__ W, u16* __restrict__ hamF,
                                              float* __restrict__ s1, float* __restrict__ s2,
                                              float* __restrict__ cs, float* __restrict__ cq) {
    const int idx = blockIdx.x * 256 + threadIdx.x;   // 65536
    if (idx < N_NODES) { s1[idx] = 0.f; s2[idx] = 0.f; }
    if (idx < OUT_F)   { cs[idx] = 0.f; cq[idx] = 0.f; }
    const int c = idx >> 9, k = idx & 511;
    const int b = c >> 5, cc = c & 31, kp = k >> 7, kq = k & 127;
    const u32 NEGMASK = 0x284Eu;     // bit (b*4+kp) set => sign -1
    const float sg = ((NEGMASK >> (b * 4 + kp)) & 1u) ? -1.f : 1.f;
    const int kappa = k >> 5, q = (k >> 3) & 3, e = k & 7;
    hamF[((kappa * 4 + q) * 128 + c) * 8 + e] = f2bf_rtn(sg * W[kq * 128 + (b ^ kp) * 32 + cc]);
}

// ---------------- h = input @ ham via MFMA; LDS-staged bf16 A (once), fragment-ordered B ----------------
// grid 512 x 256 thr. Block: 16 i-rows x 128 c; wave w owns K-slice [w*128, w*128+128).
__global__ __launch_bounds__(256) void k_h(const float* __restrict__ inp, const u16* __restrict__ hamF,
                                           const float* __restrict__ a,
                                           u16* __restrict__ hT, float* __restrict__ s1, float* __restrict__ s2) {
    __shared__ u16 inA[16 * ISTR];         // 16640 B bf16 input tile
    __shared__ float red[4][128][20];      // 40960 B; [wave][c][i_local(16)+pad4]
    const int t = threadIdx.x;
    const int lane = t & 63, wid = t >> 6;
    const int quad = lane >> 4, n = lane & 15;
    const int i0 = blockIdx.x * 16;
    const int kb = wid * 128;

    // stage 16 rows x 512 f32 -> bf16 LDS, coalesced (4KB contiguous per pass)
#pragma unroll
    for (int u = 0; u < 8; ++u) {
        float4 v = *(const float4*)&inp[(size_t)i0 * IN_F + u * 1024 + t * 4];
        const int r = u * 2 + (t >> 7);
        const int col = (t & 127) * 4;
        u64 pk = (u64)f2bf_rtn(v.x) | ((u64)f2bf_rtn(v.y) << 16)
               | ((u64)f2bf_rtn(v.z) << 32) | ((u64)f2bf_rtn(v.w) << 48);
        *(u64*)&inA[r * ISTR + col] = pk;
    }
    __syncthreads();

    floatx4 acc[8];
#pragma unroll
    for (int ct = 0; ct < 8; ++ct) acc[ct] = (floatx4){0.f, 0.f, 0.f, 0.f};

#pragma unroll
    for (int ks = 0; ks < 4; ++ks) {
        short8 fa = *(const short8*)&inA[n * ISTR + kb + ks * 32 + quad * 8];
#pragma unroll
        for (int ct = 0; ct < 8; ++ct) {
            short8 fb = *(const short8*)&hamF[((wid * 4 + ks) * 4 + quad) * 1024 + (ct * 16 + n) * 8];
            acc[ct] = __builtin_amdgcn_mfma_f32_16x16x32_bf16(fa, fb, acc[ct], 0, 0, 0);
        }
    }

    // s1/s2 partials (this wave's K-slice; full c) -> global atomics
    {
        float p1[4] = {0.f, 0.f, 0.f, 0.f}, p2[4] = {0.f, 0.f, 0.f, 0.f};
#pragma unroll
        for (int ct = 0; ct < 8; ++ct) {
            const int c = ct * 16 + n;
            const float a1v = a[c], a2v = a[OUT_F + c];
#pragma unroll
            for (int r = 0; r < 4; ++r) { p1[r] += acc[ct][r] * a1v; p2[r] += acc[ct][r] * a2v; }
        }
#pragma unroll
        for (int m = 1; m < 16; m <<= 1) {
#pragma unroll
            for (int r = 0; r < 4; ++r) {
                p1[r] += __shfl_xor(p1[r], m, 64);
                p2[r] += __shfl_xor(p2[r], m, 64);
            }
        }
        if (n == 0) {
#pragma unroll
            for (int r = 0; r < 4; ++r) {
                atomicAdd(&s1[i0 + quad * 4 + r], p1[r]);
                atomicAdd(&s2[i0 + quad * 4 + r], p2[r]);
            }
        }
    }

    // cross-wave reduce -> hT (bf16, [c][i] layout)
#pragma unroll
    for (int ct = 0; ct < 8; ++ct)
        *(float4*)&red[wid][ct * 16 + n][quad * 4] = *(float4*)&acc[ct];
    __syncthreads();

    {
        const int c = t >> 1, ih = (t & 1) * 8;
        float v[8];
#pragma unroll
        for (int e = 0; e < 8; ++e)
            v[e] = red[0][c][ih + e] + red[1][c][ih + e] + red[2][c][ih + e] + red[3][c][ih + e];
        uint4 pk;
        pk.x = (u32)f2bf_rtn(v[0]) | ((u32)f2bf_rtn(v[1]) << 16);
        pk.y = (u32)f2bf_rtn(v[2]) | ((u32)f2bf_rtn(v[3]) << 16);
        pk.z = (u32)f2bf_rtn(v[4]) | ((u32)f2bf_rtn(v[5]) << 16);
        pk.w = (u32)f2bf_rtn(v[6]) | ((u32)f2bf_rtn(v[7]) << 16);
        *(uint4*)&hT[(size_t)c * N_NODES + i0 + ih] = pk;
    }
}

// ---------------- fused MFMA attention (R14 body) + global_load_lds DMA staging ----------------
// grid (128, NSPLIT=16) x 256 thr. Block: 64 i x 128 c over JSPAN=512 j; 2 groups x 4 chunks of 64 j.
// Staging change vs R14 (the validated 441us body): hs chunks land via global_load_lds DMA —
// LINEAR LDS dest (wave-uniform ps*2048 + wid*512, + lane*16B by HW) with PRE-SWIZZLED per-lane
// global source (dcol = ((t&7)^((t>>3)&7))*8), landing bit-identically to R14's XOR-swizzled
// layout (slot s of row cr holds hT col (s^(cr&7))*8 — read side untouched). Deletes the H[4]
// reg-prefetch (-16 VGPR) and the per-chunk LDS-write block: pressure strictly DOWN vs R14's
// clean-allocating 84-VGPR body (R9/R12/R13 spill-flip lesson). DMA drains at the existing
// end-of-chunk barrier's vmcnt(0). Chunk-0 DMA issued before phase A (adj stream covers it).
__global__ __launch_bounds__(256, 4) void k_att(const int* __restrict__ adj, const u16* __restrict__ hT,
                                                const float* __restrict__ s1, const float* __restrict__ s2,
                                                float* __restrict__ Opart, float* __restrict__ Lpart) {
    __shared__ u16 hs[2][128 * 64];        // 2 x 16384 B, XOR-swizzled rows (landed via DMA)
    __shared__ float s2s[JSPAN];           // 2 KB
    const int t = threadIdx.x;
    const int lane = t & 63, wid = t >> 6;
    const int quad = lane >> 4, n = lane & 15;
    const int i0 = blockIdx.x * TILE_I;
    const int jbase = blockIdx.y * JSPAN;
    const int i_lane = i0 + wid * 16 + n;
    const float s1v = s1[i_lane];

    // DMA staging geometry: lane serves linear LDS slot (t>>3 row, t&7 slot) = base + lane*16B;
    // global source col pre-swizzled so the landed layout matches the swizzled read side.
    const int drow = t >> 3;                               // c-row within 32-row pass
    const int dcol = ((t & 7) ^ ((t >> 3) & 7)) * 8;       // pre-swizzled source column (shorts)

#define STAGE_CH(buf, chn) do {                                                              \
    _Pragma("unroll")                                                                        \
    for (int ps = 0; ps < 4; ++ps) {                                                         \
        const u16* gs = hT + (size_t)(ps * 32 + drow) * N_NODES + jbase + (chn) * 64 + dcol; \
        u16* ls = &hs[buf][0] + ps * 2048 + wid * 512;                                       \
        __builtin_amdgcn_global_load_lds((const __attribute__((address_space(1))) u32*)gs,   \
                                         (__attribute__((address_space(3))) u32*)ls,         \
                                         16, 0, 0);                                          \
    }                                                                                        \
} while (0)

    // ---- issue chunk-0 DMA first: phase A's adj stream covers its latency ----
    STAGE_CH(0, 0);

    if (t < JSPAN / 4)
        *(float4*)&s2s[t * 4] = *(const float4*)&s2[jbase + t * 4];

    // ---- Phase A: ballot-pack adj rows; lane n keeps row (wid*16+n)'s masks in regs ----
    u32 M[NGRP][8];
#pragma unroll
    for (int g = 0; g < NGRP; ++g)
#pragma unroll
        for (int w = 0; w < 8; ++w) M[g][w] = 0u;
    {
        const size_t rowbase = (size_t)(i0 + wid * 16);
        const int* aj = adj + jbase + lane * 4;
#pragma unroll 4
        for (int rr = 0; rr < 16; ++rr) {
            const int* ap = aj + (rowbase + rr) * N_NODES;
            uint4 v[NGRP];
#pragma unroll
            for (int g = 0; g < NGRP; ++g) v[g] = *(const uint4*)(ap + g * 256);
#pragma unroll
            for (int g = 0; g < NGRP; ++g) BALLOT4(v[g], rr, M[g]);
        }
    }
    __syncthreads();   // drains vmcnt(0): chunk-0 DMA landed; s2s visible

    floatx4 acc[8];
#pragma unroll
    for (int ct = 0; ct < 8; ct++) acc[ct] = (floatx4){0.f, 0.f, 0.f, 0.f};
    float Lacc = 0.f;

#pragma unroll
    for (int g = 0; g < NGRP; ++g) {
#pragma unroll
        for (int chi = 0; chi < 4; ++chi) {
            const int ch = g * 4 + chi;
            const int cur = ch & 1;
            const bool more = (ch + 1 < NGRP * 4);
            // issue next chunk's DMA staging (targets the other buffer; drains at this chunk's barrier)
            if (more) STAGE_CH(cur ^ 1, ch + 1);
            // build A-frags (attention weights) for this chunk's 64 j; s2 from LDS (lgkmcnt)
            short8 fa[2];
#pragma unroll
            for (int ks = 0; ks < 2; ++ks) {
                const int jl = ch * 64 + ks * 32 + quad * 8;
                float4 sa = *(const float4*)&s2s[jl];
                float4 sb = *(const float4*)&s2s[jl + 4];
                const float sv[8] = {sa.x, sa.y, sa.z, sa.w, sb.x, sb.y, sb.z, sb.w};
                union { u32 u[4]; short8 s; } cv;
#pragma unroll
                for (int jh = 0; jh < 4; ++jh) {
                    float w2[2];
#pragma unroll
                    for (int e = 0; e < 2; ++e) {
                        const int jj = jh * 2 + e;
                        const u32 word = M[g][(jj & 3) * 2 + (chi >> 1)];   // all-static reg index
                        const int sh = (chi & 1) * 16 + ks * 8 + quad * 2 + (jj >> 2);
                        const u32 mbit = (word >> sh) & 1u;
                        float sc = s1v + sv[jj];
                        sc = fmaxf(sc, LRELU_A * sc);
                        float w = mbit ? __expf(sc - MSH) : 0.f;
                        Lacc += w;
                        w2[e] = w;
                    }
                    cv.u[jh] = (u32)f2bf_rtn(w2[0]) | ((u32)f2bf_rtn(w2[1]) << 16);
                }
                fa[ks] = cv.s;
            }
            // 16 MFMAs from LDS (swizzled reads: conflict-free; identical to R14)
#pragma unroll
            for (int ct = 0; ct < 8; ++ct) {
                const int rb = ct * 16 + n;
                const int sw = (rb & 7) * 8;
                short8 fb0 = *(const short8*)&hs[cur][rb * 64 + ((quad * 8) ^ sw)];
                short8 fb1 = *(const short8*)&hs[cur][rb * 64 + ((32 + quad * 8) ^ sw)];
                acc[ct] = __builtin_amdgcn_mfma_f32_16x16x32_bf16(fa[0], fb0, acc[ct], 0, 0, 0);
                acc[ct] = __builtin_amdgcn_mfma_f32_16x16x32_bf16(fa[1], fb1, acc[ct], 0, 0, 0);
            }
            __syncthreads();   // drains vmcnt(0): next chunk's DMA landed; hs[cur] free
        }
    }

    // L row-sum across quads
    Lacc += __shfl_xor(Lacc, 16, 64);
    Lacc += __shfl_xor(Lacc, 32, 64);
    if (lane < 16)
        Lpart[(size_t)blockIdx.y * N_NODES + i_lane] = Lacc;

    // O partials (C layout: row = quad*4+reg, col = ct*16+n)
    const size_t obase = (size_t)blockIdx.y * N_NODES * OUT_F;
#pragma unroll
    for (int ct = 0; ct < 8; ++ct) {
#pragma unroll
        for (int r = 0; r < 4; ++r) {
            const int i = i0 + wid * 16 + quad * 4 + r;
            Opart[obase + (size_t)i * OUT_F + ct * 16 + n] = acc[ct][r];
        }
    }
#undef STAGE_CH
}

// ---------------- combine partials, normalize, column stats via atomics ----------------
// grid 512 x 256 thr; block = 16 i-rows
__global__ __launch_bounds__(256) void k_comb(const float* __restrict__ Opart, const float* __restrict__ Lpart,
                                              float* __restrict__ hp, float* __restrict__ cs, float* __restrict__ cq) {
    const int t = threadIdx.x;
    const int c = t & 127, half = t >> 7;
    const int ibase = blockIdx.x * 16;
    float sv = 0.f, sq = 0.f;
    for (int k = 0; k < 8; k++) {
        const int i = ibase + half + (k << 1);
        float o = 0.f, L = 0.f;
#pragma unroll
        for (int s = 0; s < NSPLIT; s++) {
            o += Opart[((size_t)s * N_NODES + i) * OUT_F + c];
            L += Lpart[(size_t)s * N_NODES + i];
        }
        float v = L > 0.f ? o / L : 0.f;
        hp[(size_t)i * OUT_F + c] = v;
        sv += v; sq += v * v;
    }
    __shared__ float red[256];
    red[t] = sv; __syncthreads();
    if (half == 0) atomicAdd(&cs[c], sv + red[t + 128]);
    __syncthreads(); red[t] = sq; __syncthreads();
    if (half == 0) atomicAdd(&cq[c], sq + red[t + 128]);
}

// ---------------- batchnorm + elu + f32 out ----------------
__global__ __launch_bounds__(256) void k_bn(const float* __restrict__ hp, const float* __restrict__ cs,
                                            const float* __restrict__ cq, const float* __restrict__ gamma,
                                            const float* __restrict__ beta, float* __restrict__ out) {
    const int idx = blockIdx.x * 256 + threadIdx.x;   // 1M
    const int c = idx & 127;
    const float mean = cs[c] * (1.f / N_NODES);
    const float var  = cq[c] * (1.f / N_NODES) - mean * mean;
    float x = (hp[idx] - mean) * rsqrtf(var + EPS_BN) * gamma[c] + beta[c];
    x = x > 0.f ? x : expm1f(x);
    out[idx] = x;
}

extern "C" void kernel_launch(void* const* d_in, const int* in_sizes, int n_in,
                              void* d_out, int out_size, void* d_ws, size_t ws_size,
                              hipStream_t stream) {
    (void)in_sizes; (void)n_in; (void)out_size; (void)ws_size;
    const float* inp   = (const float*)d_in[0];
    const int*   adj   = (const int*)d_in[1];
    const float* W     = (const float*)d_in[2];
    const float* a     = (const float*)d_in[3];
    const float* gamma = (const float*)d_in[4];
    const float* beta  = (const float*)d_in[5];
    float* out = (float*)d_out;

    char* wsb = (char*)d_ws;
    u16*   hamF = (u16*)wsb;   wsb += (size_t)OUT_F * IN_F * 2;               // 128 KB
    u16*   hT   = (u16*)wsb;   wsb += (size_t)OUT_F * N_NODES * 2;            // 2 MB
    float* s1   = (float*)wsb; wsb += N_NODES * 4;
    float* s2   = (float*)wsb; wsb += N_NODES * 4;
    float* Op   = (float*)wsb; wsb += (size_t)NSPLIT * N_NODES * OUT_F * 4;   // 64 MB
    float* Lp   = (float*)wsb; wsb += (size_t)NSPLIT * N_NODES * 4;
    float* hp   = (float*)wsb; wsb += (size_t)N_NODES * OUT_F * 4;            // 4 MB
    float* cs   = (float*)wsb; wsb += OUT_F * 4;
    float* cq   = (float*)wsb; wsb += OUT_F * 4;

    hipLaunchKernelGGL(k_hamT, dim3(256), dim3(256), 0, stream, W, hamF, s1, s2, cs, cq);
    hipLaunchKernelGGL(k_h,    dim3(512), dim3(256), 0, stream, inp, hamF, a, hT, s1, s2);
    hipLaunchKernelGGL(k_att,  dim3(128, NSPLIT), dim3(256), 0, stream, adj, hT, s1, s2, Op, Lp);
    hipLaunchKernelGGL(k_comb, dim3(512), dim3(256), 0, stream, Op, Lp, hp, cs, cq);
    hipLaunchKernelGGL(k_bn,   dim3(4096), dim3(256), 0, stream, hp, cs, cq, gamma, beta, out);
}